// Round 8
// baseline (81.842 us; speedup 1.0000x reference)
//
#include <hip/hip_runtime.h>
#include <math.h>

#define THREADS 256
#define BPB 8      // bins per term1 group
#define PCH 16     // pixel chunks per term1 group

// ws layout (bytes) — ALL REGIONS DISJOINT (R6/R7 bug: pmax[1024..3072) overlapped psumd@2048):
//   0:    uint   c0         (phase-0 ticket, init 0)
//   64:   uint   c1         (phase-2 ticket, init 0)
//   128:  uint   go         (barrier flag; master stores bits(1/tmax) -- nonzero)
//   192:  float  bmax       (by k_init; cross-dispatch -> plain load safe)
//   2048: double psumd[8]   (64B-strided accumulators, init 0)          [2048,2552)
//   4096: uint   pmax[G1]   (per-term1-block tmax partial bits)         [4096,6144)
//   8192: uint   binmin[nb] (ordered-key minima, init 0xFFFFFFFF)       [8192,9216)

__device__ __forceinline__ float wmaxAll(float v) {
  #pragma unroll
  for (int o = 32; o > 0; o >>= 1) v = fmaxf(v, __shfl_xor(v, o, 64));
  return v;
}
__device__ __forceinline__ float wminAll(float v) {
  #pragma unroll
  for (int o = 32; o > 0; o >>= 1) v = fminf(v, __shfl_xor(v, o, 64));
  return v;
}
__device__ __forceinline__ float wsumAll(float v) {
  #pragma unroll
  for (int o = 32; o > 0; o >>= 1) v += __shfl_xor(v, o, 64);
  return v;
}
__device__ __forceinline__ double wsumAllD(double v) {
  #pragma unroll
  for (int o = 32; o > 0; o >>= 1) v += __shfl_xor(v, o, 64);
  return v;
}

// totally-ordered uint key for float (handles negatives)
__device__ __forceinline__ unsigned keyEnc(float f) {
  unsigned u = __float_as_uint(f);
  return (u & 0x80000000u) ? ~u : (u | 0x80000000u);
}
__device__ __forceinline__ float keyDec(unsigned k) {
  unsigned u = (k & 0x80000000u) ? (k ^ 0x80000000u) : ~k;
  return __uint_as_float(u);
}

__device__ __forceinline__ unsigned aload(const unsigned* p) {
  return __hip_atomic_load(p, __ATOMIC_RELAXED, __HIP_MEMORY_SCOPE_AGENT);
}
__device__ __forceinline__ void astore(unsigned* p, unsigned v) {
  __hip_atomic_store(p, v, __ATOMIC_RELAXED, __HIP_MEMORY_SCOPE_AGENT);
}

__global__ __launch_bounds__(64) void k_init(const float* __restrict__ bins, int nb,
                                             unsigned* __restrict__ c0,
                                             unsigned* __restrict__ c1,
                                             unsigned* __restrict__ go,
                                             float* __restrict__ bmax,
                                             double* __restrict__ psumd,
                                             unsigned* __restrict__ binmin) {
  const int tid = threadIdx.x;
  for (int i = tid; i < nb; i += 64) binmin[i] = 0xFFFFFFFFu;
  if (tid < 8) psumd[tid * 8] = 0.0;
  if (tid == 0) { *c0 = 0u; *c1 = 0u; *go = 0u; }
  float bv = 0.0f;
  for (int i = tid; i < nb; i += 64) bv = fmaxf(bv, bins[i]);
  bv = wmaxAll(bv);
  if (tid == 0) *bmax = bv;
}

// blocks [0, NT2):      term2 (one float4/thread); preload pixels, spin on go
// blocks [NT2, NT2+G1): term1; phase-0 tmax partial; last-arriving = master
__global__ __launch_bounds__(THREADS) void k_fused(const float4* __restrict__ t4, int n4,
                                                   const float* __restrict__ t, int n,
                                                   const float* __restrict__ bins, int nb,
                                                   unsigned* __restrict__ c0,
                                                   unsigned* __restrict__ c1,
                                                   unsigned* __restrict__ go,
                                                   const float* __restrict__ bmaxp,
                                                   unsigned* __restrict__ pmax,
                                                   double* __restrict__ psumd,
                                                   unsigned* __restrict__ binmin,
                                                   float* __restrict__ out,
                                                   int NT2, int G1, int G) {
  __shared__ float sred[4];
  __shared__ float sb[256], hb[256];
  __shared__ float sm1[4 * BPB];
  __shared__ float ss[4];
  __shared__ double ds[4];
  __shared__ unsigned sold, sgo, sticket;

  const int tid = threadIdx.x;
  const int lane = tid & 63, w = tid >> 6;
  const int bid = blockIdx.x;
  const int ntail = n - n4 * 4;
  const float ibf = 1.0f / *bmaxp;  // cross-dispatch (k_init) -> plain load safe

  if (bid < NT2) {
    // ================= term2 block =================
    const int idx = bid * THREADS + tid;
    float4 a = make_float4(0.f, 0.f, 0.f, 0.f);
    const bool has = (idx < n4);
    if (has) a = t4[idx];  // pre-issue pixel load; latency hides under the spin
    for (int i = tid; i < nb && i < 256; i += THREADS) {
      float b = bins[i] * ibf;
      sb[i] = b * b;
      hb[i] = -(b + b);
    }
    if (tid == 0) {
      unsigned gv;
      while ((gv = aload(go)) == 0u) __builtin_amdgcn_s_sleep(4);
      sgo = gv;
    }
    __syncthreads();
    const float itf = __uint_as_float(sgo);

    float lsum = 0.0f;
    if (has) {
      float t0 = a.x * itf, t1 = a.y * itf, t2 = a.z * itf, t3 = a.w * itf;
      float m0 = 1e30f, m1 = 1e30f, m2 = 1e30f, m3 = 1e30f;
      #pragma unroll 8
      for (int j = 0; j < nb; j++) {
        float s = sb[j], h = hb[j];
        m0 = fminf(m0, fmaf(h, t0, s));
        m1 = fminf(m1, fmaf(h, t1, s));
        m2 = fminf(m2, fmaf(h, t2, s));
        m3 = fminf(m3, fmaf(h, t3, s));
      }
      lsum = (fmaf(t0, t0, m0) + fmaf(t1, t1, m1)) + (fmaf(t2, t2, m2) + fmaf(t3, t3, m3));
    }
    if (bid == 0 && tid < ntail) {
      float tv = t[n4 * 4 + tid] * itf;
      float m = 1e30f;
      for (int j = 0; j < nb; j++) m = fminf(m, fmaf(hb[j], tv, sb[j]));
      lsum += fmaf(tv, tv, m);
    }
    float s = wsumAll(lsum);
    if (lane == 0) ss[w] = s;
    __syncthreads();
    if (tid == 0)
      atomicAdd(&psumd[(bid & 7) * 8], (double)((ss[0] + ss[1]) + (ss[2] + ss[3])));
  } else {
    // ================= term1 block =================
    const int b1 = bid - NT2;
    // ---- phase 0: this block's slice of the target-max ----
    float v = 0.0f;
    const int stride0 = G1 * THREADS;
    for (int i = b1 * THREADS + tid; i < n4; i += stride0) {
      float4 a = t4[i];
      v = fmaxf(v, fmaxf(fmaxf(a.x, a.y), fmaxf(a.z, a.w)));
    }
    for (int i = n4 * 4 + b1 * THREADS + tid; i < n; i += stride0) v = fmaxf(v, t[i]);
    v = wmaxAll(v);
    if (lane == 0) sred[w] = v;
    __syncthreads();
    if (tid == 0) {
      float p = fmaxf(fmaxf(sred[0], sred[1]), fmaxf(sred[2], sred[3]));
      astore(&pmax[b1], __float_as_uint(p));             // coherent partial
      asm volatile("s_waitcnt vmcnt(0)" ::: "memory");   // store acked before ticket
      sold = atomicAdd(c0, 1u);
    }
    __syncthreads();
    if (sold == (unsigned)(G1 - 1)) {
      // ---- master: reduce partials, broadcast 1/T via go ----
      float m = 0.0f;
      for (int i = tid; i < G1; i += THREADS) m = fmaxf(m, __uint_as_float(aload(&pmax[i])));
      m = wmaxAll(m);
      if (lane == 0) sred[w] = m;
      __syncthreads();
      if (tid == 0) {
        float T = fmaxf(fmaxf(sred[0], sred[1]), fmaxf(sred[2], sred[3]));
        unsigned gv = __float_as_uint(1.0f / T);          // > 0, so nonzero bits
        astore(go, gv);
        sgo = gv;
      }
      __syncthreads();
    } else {
      if (tid == 0) {
        unsigned gv;
        while ((gv = aload(go)) == 0u) __builtin_amdgcn_s_sleep(4);
        sgo = gv;
      }
      __syncthreads();
    }
    const float itf = __uint_as_float(sgo);

    // ---- term1 work: bin-group g, pixel-chunk c ----
    const int g = b1 / PCH, c = b1 % PCH;
    const int base = g * BPB;
    float bn[BPB], mn[BPB];
    #pragma unroll
    for (int k = 0; k < BPB; k++) {
      int bi = base + k;
      bn[k] = (bi < nb) ? bins[bi] * ibf : 3e30f;
      mn[k] = 1e30f;  // min over pixels of (t^2 - 2bt); b^2 re-added in finalize
    }
    const int chunk = (n4 + PCH - 1) / PCH;
    const int lo = c * chunk;
    const int hi = (lo + chunk < n4) ? lo + chunk : n4;
    for (int i = lo + tid; i < hi; i += THREADS) {
      float4 a = t4[i];
      float t0 = a.x * itf, t1 = a.y * itf, t2 = a.z * itf, t3 = a.w * itf;
      float s0 = t0 * t0, s1 = t1 * t1, s2 = t2 * t2, s3 = t3 * t3;
      float h0 = -(t0 + t0), h1 = -(t1 + t1), h2 = -(t2 + t2), h3 = -(t3 + t3);
      #pragma unroll
      for (int k = 0; k < BPB; k++) {
        float b = bn[k];
        mn[k] = fminf(mn[k], fmaf(h0, b, s0));
        mn[k] = fminf(mn[k], fmaf(h1, b, s1));
        mn[k] = fminf(mn[k], fmaf(h2, b, s2));
        mn[k] = fminf(mn[k], fmaf(h3, b, s3));
      }
    }
    if (c == 0 && tid < ntail) {
      float tv = t[n4 * 4 + tid] * itf;
      float s = tv * tv, h = -(tv + tv);
      #pragma unroll
      for (int k = 0; k < BPB; k++) mn[k] = fminf(mn[k], fmaf(h, bn[k], s));
    }
    #pragma unroll
    for (int k = 0; k < BPB; k++) {
      float m = wminAll(mn[k]);
      if (lane == 0) sm1[w * BPB + k] = m;
    }
    __syncthreads();
    if (tid < BPB && base + tid < nb) {
      float m = fminf(fminf(sm1[tid], sm1[BPB + tid]),
                      fminf(sm1[2 * BPB + tid], sm1[3 * BPB + tid]));
      atomicMin(&binmin[base + tid], keyEnc(m));
    }
  }

  // ================= phase 2: last-block finalize =================
  asm volatile("s_waitcnt vmcnt(0)" ::: "memory");  // our atomics acked
  if (tid == 0) sticket = atomicAdd(c1, 1u);
  __syncthreads();
  if (sticket == (unsigned)(G - 1)) {
    double tsum = 0.0;
    for (int b = tid; b < nb; b += THREADS) {
      float m = keyDec(aload(&binmin[b]));
      float bnv = bins[b] * ibf;
      float val = fmaf(bnv, bnv, m);            // add back b^2
      tsum += (m < 1e29f) ? (double)val : 0.0;  // all-inf row -> 0 per reference
    }
    if (tid < 8)
      tsum += __hip_atomic_load(&psumd[tid * 8], __ATOMIC_RELAXED, __HIP_MEMORY_SCOPE_AGENT);
    tsum = wsumAllD(tsum);
    if (lane == 0) ds[w] = tsum;
    __syncthreads();
    if (tid == 0) out[0] = (float)((ds[0] + ds[1]) + (ds[2] + ds[3]));
  }
}

extern "C" void kernel_launch(void* const* d_in, const int* in_sizes, int n_in,
                              void* d_out, int out_size, void* d_ws, size_t ws_size,
                              hipStream_t stream) {
  const float* target = (const float*)d_in[0];
  const float* bins = (const float*)d_in[1];
  const int n = in_sizes[0];   // 307200
  const int nb = in_sizes[1];  // 256
  float* out = (float*)d_out;

  unsigned* c0 = (unsigned*)d_ws;
  unsigned* c1 = (unsigned*)((char*)d_ws + 64);
  unsigned* go = (unsigned*)((char*)d_ws + 128);
  float* bmax = (float*)((char*)d_ws + 192);
  double* psumd = (double*)((char*)d_ws + 2048);     // [2048, 2552)
  unsigned* pmax = (unsigned*)((char*)d_ws + 4096);  // [4096, 6144)
  unsigned* binmin = (unsigned*)((char*)d_ws + 8192);// [8192, 9216)

  const int n4 = n / 4;
  const float4* t4 = (const float4*)target;

  k_init<<<1, 64, 0, stream>>>(bins, nb, c0, c1, go, bmax, psumd, binmin);

  const int NT2 = (n4 + THREADS - 1) / THREADS;   // 300 term2 blocks
  const int G1 = ((nb + BPB - 1) / BPB) * PCH;    // 512 term1 blocks
  const int G = NT2 + G1;                         // 812 blocks, all co-resident
  k_fused<<<G, THREADS, 0, stream>>>(t4, n4, target, n, bins, nb,
                                     c0, c1, go, bmax, pmax, psumd, binmin,
                                     out, NT2, G1, G);
}